// Round 11
// baseline (161.785 us; speedup 1.0000x reference)
//
#include <hip/hip_runtime.h>
#include <hip/hip_bf16.h>

// CACE message passing. MAX_L=3 -> NL=20, N_RBF=8, RB=8, K=3 -> C=9, NB=5,
// CUTOFF=5.5, T_MP=1, MP_NORM=0.2, N=2000, E=50000. fp32 I/O.
// Round 17: best-measured structure (r9, 150.7us) + A/B0 ROUND-TRIP
// ELIMINATION isolated from any structure change.
//  - k_nodeA no longer writes A (11.5 MB) or B0 (2.9 MB); only Abf2 + chi.
//  - k_node2 re-accumulates acc (+8 FMA/edge/thread on 20%-busy VALU, free)
//    inside its existing interleaved loops, rebuilds Ab and Bsh1 in LDS
//    (r10 proved this recompute path numerically sound, absmax 0.0625).
//  - everything else verbatim r9: 1-block fused prep (count+rank+scan),
//    64-thr k_edge, paired node blocks with interleaved 2x-MLP edge loops.
// Row (48 floats): [0:8] g, [8:16] fr, [16:36] ang, [36:45] enc, [45:48] pad.

#define CUTF 5.5f
#define MPNORM 0.2f

__constant__ int   d_DEGS[20]  = {0,1,1,1,2,2,2,2,2,2,3,3,3,3,3,3,3,3,3,3};
__constant__ float d_MULTI[20] = {1,1,1,1,1,2,2,1,2,1,1,3,3,3,6,3,1,3,3,1};

// ------ count + rank + exclusive scan, one block (N<=2048, 1024 thr) --------
__global__ __launch_bounds__(1024) void k_prep(const int* __restrict__ eidx,
                                               int* __restrict__ offs,
                                               int* __restrict__ erank,
                                               int N, int E) {
  __shared__ int cnt[2048];
  __shared__ int part[1024];
  int t = threadIdx.x;
  cnt[t] = 0; cnt[t + 1024] = 0;
  __syncthreads();
  const int* recv = eidx + E;
  if ((E & 3) == 0) {
    for (int i = t * 4; i + 3 < E; i += 4096) {
      int4 v = *reinterpret_cast<const int4*>(recv + i);
      int r0 = atomicAdd(&cnt[v.x], 1);
      int r1 = atomicAdd(&cnt[v.y], 1);
      int r2 = atomicAdd(&cnt[v.z], 1);
      int r3 = atomicAdd(&cnt[v.w], 1);
      *reinterpret_cast<int4*>(erank + i) = make_int4(r0, r1, r2, r3);
    }
  } else {
    for (int i = t; i < E; i += 1024) erank[i] = atomicAdd(&cnt[recv[i]], 1);
  }
  __syncthreads();
  int a = cnt[2 * t], b = cnt[2 * t + 1];
  int s = a + b;
  part[t] = s;
  __syncthreads();
  for (int d = 1; d < 1024; d <<= 1) {
    int add = (t >= d) ? part[t - d] : 0;
    __syncthreads();
    part[t] += add;
    __syncthreads();
  }
  int excl = part[t] - s;
  if (2 * t     < N) offs[2 * t]     = excl;
  if (2 * t + 1 < N) offs[2 * t + 1] = excl + a;
  if (t == 1023) offs[N] = part[1023];
}

// ------------- per-edge compute, scattered directly into CSR slot ------------
__global__ __launch_bounds__(64) void k_edge(
                       const float* __restrict__ pos,
                       const float* __restrict__ shifts,
                       const float* __restrict__ Wemb,
                       const float* __restrict__ War,
                       const int* __restrict__ species,
                       const int* __restrict__ eidx,
                       const int* __restrict__ offs,
                       const int* __restrict__ erank,
                       float* __restrict__ edata,
                       int* __restrict__ esend,
                       int E) {
  __shared__ float war_s[64];
  int t = threadIdx.x;
  war_s[t] = War[t];
  __syncthreads();
  int e = blockIdx.x * 64 + t;
  if (e >= E) return;
  int s  = eidx[e];
  int rI = eidx[E + e];
  int rk = erank[e];
  float vx = pos[rI*3+0] - pos[s*3+0] + shifts[e*3+0];
  float vy = pos[rI*3+1] - pos[s*3+1] + shifts[e*3+1];
  float vz = pos[rI*3+2] - pos[s*3+2] + shifts[e*3+2];
  float len = sqrtf(vx*vx + vy*vy + vz*vz);
  float inv = 1.0f / (len + 1e-9f);
  float ux = vx*inv, uy = vy*inv, uz = vz*inv;
  float uu = len * (1.0f/CUTF);
  float u2 = uu*uu, u6 = u2*u2*u2;
  float fcut = (uu < 1.0f) ? (1.0f - 28.0f*u6 + 48.0f*u6*uu - 21.0f*u6*u2) : 0.0f;
  float x = 3.14159265358979f * uu;
  float sn = sinf(x), c2 = 2.0f*cosf(x), snm1 = 0.0f;
  float pref = sqrtf(2.0f/CUTF) / (len + 1e-20f);
  float rad[8];
  float v[48];
  #pragma unroll
  for (int k = 0; k < 8; k++) {
    rad[k] = pref * sn;
    v[k]   = rad[k] * fcut;           // g
    float nxt = c2*sn - snm1; snm1 = sn; sn = nxt;
  }
  #pragma unroll
  for (int b = 0; b < 8; b++) {       // fr = (rad @ W_ar) * fcut
    float a = 0.0f;
    #pragma unroll
    for (int k = 0; k < 8; k++) a += rad[k] * war_s[k*8+b];
    v[8+b] = a * fcut;
  }
  float px2 = ux*ux, py2 = uy*uy, pz2 = uz*uz;
  v[16] = 1.0f; v[17] = ux;     v[18] = uy;     v[19] = uz;
  v[20] = px2;  v[21] = ux*uy;  v[22] = ux*uz;  v[23] = py2;
  v[24] = uy*uz;v[25] = pz2;
  v[26] = px2*ux; v[27] = px2*uy; v[28] = px2*uz; v[29] = ux*py2;
  v[30] = ux*uy*uz; v[31] = ux*pz2; v[32] = py2*uy; v[33] = py2*uz;
  v[34] = uy*pz2; v[35] = pz2*uz;
  int zs = species[s], zr = species[rI];
  float es0 = Wemb[zs*3+0], es1 = Wemb[zs*3+1], es2 = Wemb[zs*3+2];
  float er0 = Wemb[zr*3+0], er1 = Wemb[zr*3+1], er2 = Wemb[zr*3+2];
  v[36] = es0*er0; v[37] = es0*er1; v[38] = es0*er2;
  v[39] = es1*er0; v[40] = es1*er1; v[41] = es1*er2;
  v[42] = es2*er0; v[43] = es2*er1; v[44] = es2*er2;
  v[45] = 0.0f; v[46] = 0.0f; v[47] = 0.0f;
  int dst = offs[rI] + rk;
  float4* eb4 = reinterpret_cast<float4*>(edata + (size_t)dst * 48);
  #pragma unroll
  for (int w = 0; w < 12; w++)
    eb4[w] = make_float4(v[4*w], v[4*w+1], v[4*w+2], v[4*w+3]);
  esend[dst] = s;
}

// --------- per-node phase 1 (node PAIR per block, interleaved loops) ---------
// nodes n0=2*bid, n1=2*bid+1; thread t<180 owns (l=t/9, c=t%9).
// Outputs ONLY Abf2 (bf16-packed) + chi. No A / B0 round-trip.
__global__ __launch_bounds__(192) void k_nodeA(
    const float* __restrict__ edata, const int* __restrict__ offs,
    const float* __restrict__ Wrad, const float* __restrict__ Wchi,
    uint4* __restrict__ Abf2, float* __restrict__ chi, int N) {
  __shared__ float wr_s[288];        // [deg][r][b], deg stride 72
  __shared__ float wchi_s[40];       // [b][k]
  __shared__ float Bsh[2][360];      // [q][b*45 + k*9 + c]
  int t = threadIdx.x;
  int n0 = blockIdx.x * 2, n1 = n0 + 1;
  for (int i = t; i < 256; i += 192) { int d = i >> 6, rm = i & 63; wr_s[d*72+rm] = Wrad[i]; }
  for (int i = t; i < 40;  i += 192) wchi_s[i] = Wchi[i];
  for (int i = t; i < 720; i += 192) (&Bsh[0][0])[i] = 0.0f;
  int l = t / 9, c = t - l*9;
  bool act = t < 180;
  int ll = act ? l : 0, cc = act ? c : 0;
  int s0 = offs[n0], m0 = offs[n0+1];
  int m1 = (n1 < N) ? offs[n0+2] : m0;
  int L0 = m0 - s0, L1 = m1 - m0;
  int Lc = (L0 < L1) ? L0 : L1;
  float acc0[8], acc1[8];
  #pragma unroll
  for (int r = 0; r < 8; r++) { acc0[r] = 0.0f; acc1[r] = 0.0f; }
  // interleaved common part: two independent chains -> 2x MLP
  #pragma unroll 2
  for (int i = 0; i < Lc; i++) {
    const float* r0 = edata + (size_t)(s0+i) * 48;
    const float* r1 = edata + (size_t)(m0+i) * 48;
    float p0 = r0[16+ll] * r0[36+cc];
    float p1 = r1[16+ll] * r1[36+cc];
    #pragma unroll
    for (int r = 0; r < 8; r++) { acc0[r] += r0[r] * p0; acc1[r] += r1[r] * p1; }
  }
  #pragma unroll 4
  for (int i = Lc; i < L0; i++) {
    const float* r0 = edata + (size_t)(s0+i) * 48;
    float p0 = r0[16+ll] * r0[36+cc];
    #pragma unroll
    for (int r = 0; r < 8; r++) acc0[r] += r0[r] * p0;
  }
  #pragma unroll 4
  for (int i = Lc; i < L1; i++) {
    const float* r1 = edata + (size_t)(m0+i) * 48;
    float p1 = r1[16+ll] * r1[36+cc];
    #pragma unroll
    for (int r = 0; r < 8; r++) acc1[r] += r1[r] * p1;
  }
  __syncthreads();   // weights/Bsh zeros visible
  int deg = act ? d_DEGS[ll] : 0;
  float mlt = d_MULTI[ll]; int kk = 1 + deg;
  const float* wp = &wr_s[deg*72];
  #pragma unroll
  for (int q = 0; q < 2; q++) {
    int n = n0 + q;
    if (n >= N) break;
    const float* ac = q ? acc1 : acc0;
    float Ab[8];
    #pragma unroll
    for (int b = 0; b < 8; b++) {
      float a = 0.0f;
      #pragma unroll
      for (int r = 0; r < 8; r++) a += ac[r] * wp[r*8+b];
      Ab[b] = a;
    }
    if (act) {
      unsigned int pk[4];
      #pragma unroll
      for (int bp = 0; bp < 4; bp++) {
        __hip_bfloat16 blo = __float2bfloat16(Ab[2*bp]);
        __hip_bfloat16 bhi = __float2bfloat16(Ab[2*bp+1]);
        pk[bp] = (unsigned int)(*reinterpret_cast<unsigned short*>(&blo))
               | ((unsigned int)(*reinterpret_cast<unsigned short*>(&bhi)) << 16);
      }
      uint4 qv; qv.x = pk[0]; qv.y = pk[1]; qv.z = pk[2]; qv.w = pk[3];
      Abf2[(size_t)n*180 + t] = qv;
      if (l == 0) {
        #pragma unroll
        for (int b = 0; b < 8; b++) Bsh[q][b*45 + c] = Ab[b];
      }
      #pragma unroll
      for (int b = 0; b < 8; b++) atomicAdd(&Bsh[q][b*45 + kk*9 + c], mlt*Ab[b]*Ab[b]);
    }
  }
  __syncthreads();
  if (t < 18) {
    int q = t / 9, tc = t - q*9;
    int n = n0 + q;
    if (n < N) {
      float s = 0.0f;
      for (int b = 0; b < 8; b++)
        #pragma unroll
        for (int kq = 0; kq < 5; kq++) s += Bsh[q][b*45 + kq*9 + tc] * wchi_s[b*5 + kq];
      chi[n*9 + tc] = s;
    }
  }
}

// --------- per-node phase 2 (node PAIR per block, acc RECOMPUTED) ------------
// Rebuilds Ab and Bsh1 locally from re-accumulated acc; no A/B0 reads.
__global__ __launch_bounds__(192) void k_node2(
    const float* __restrict__ edata, const int* __restrict__ esend,
    const int* __restrict__ offs,
    const float* __restrict__ Wrad, const float* __restrict__ Wmem,
    const uint4* __restrict__ Abf2, const float* __restrict__ chi,
    float* __restrict__ out, int N) {
  __shared__ float wr_s[288], wm_s[288];
  __shared__ float Bsh[4][360];      // [0..1]=phase1 q0/q1, [2..3]=phase2
  int t = threadIdx.x;
  int n0 = blockIdx.x * 2, n1 = n0 + 1;
  for (int i = t; i < 256; i += 192) {
    int d = i >> 6, rm = i & 63;
    wr_s[d*72+rm] = Wrad[i];
    wm_s[d*72+rm] = Wmem[i];
  }
  for (int i = t; i < 1440; i += 192) (&Bsh[0][0])[i] = 0.0f;
  int l = t / 9, c = t - l*9;
  bool act = t < 180;
  int ll = act ? l : 0, cc = act ? c : 0;
  int tt = act ? t : 0;
  int s0 = offs[n0], m0 = offs[n0+1];
  int m1 = (n1 < N) ? offs[n0+2] : m0;
  int L0 = m0 - s0, L1 = m1 - m0;
  int Lc = (L0 < L1) ? L0 : L1;
  float A0[8], A1[8], S0[8], S1[8], R0[8], R1[8];
  #pragma unroll
  for (int r = 0; r < 8; r++) {
    A0[r]=0.0f; A1[r]=0.0f; S0[r]=0.0f; S1[r]=0.0f; R0[r]=0.0f; R1[r]=0.0f;
  }
  #pragma unroll 2
  for (int i = 0; i < Lc; i++) {
    int j0 = s0 + i, j1 = m0 + i;
    const float* r0 = edata + (size_t)j0 * 48;
    const float* r1 = edata + (size_t)j1 * 48;
    int sd0 = esend[j0], sd1 = esend[j1];
    float ch0 = chi[sd0*9 + cc], ch1 = chi[sd1*9 + cc];
    const uint4 q0 = Abf2[(size_t)sd0*180 + tt];
    const uint4 q1 = Abf2[(size_t)sd1*180 + tt];
    float p0 = r0[16+ll] * r0[36+cc];
    float p1 = r1[16+ll] * r1[36+cc];
    float pc0 = p0 * ch0, pc1 = p1 * ch1;
    #pragma unroll
    for (int r = 0; r < 8; r++) {
      A0[r] += r0[r] * p0;  A1[r] += r1[r] * p1;     // acc recompute (free VALU)
      S0[r] += r0[r] * pc0; S1[r] += r1[r] * pc1;
    }
    float a0 = __uint_as_float(q0.x << 16), a1 = __uint_as_float(q0.x & 0xffff0000u);
    float a2 = __uint_as_float(q0.y << 16), a3 = __uint_as_float(q0.y & 0xffff0000u);
    float a4 = __uint_as_float(q0.z << 16), a5 = __uint_as_float(q0.z & 0xffff0000u);
    float a6 = __uint_as_float(q0.w << 16), a7 = __uint_as_float(q0.w & 0xffff0000u);
    R0[0] += a0*r0[8];  R0[1] += a1*r0[9];  R0[2] += a2*r0[10]; R0[3] += a3*r0[11];
    R0[4] += a4*r0[12]; R0[5] += a5*r0[13]; R0[6] += a6*r0[14]; R0[7] += a7*r0[15];
    float b0 = __uint_as_float(q1.x << 16), b1 = __uint_as_float(q1.x & 0xffff0000u);
    float b2 = __uint_as_float(q1.y << 16), b3 = __uint_as_float(q1.y & 0xffff0000u);
    float b4 = __uint_as_float(q1.z << 16), b5 = __uint_as_float(q1.z & 0xffff0000u);
    float b6 = __uint_as_float(q1.w << 16), b7 = __uint_as_float(q1.w & 0xffff0000u);
    R1[0] += b0*r1[8];  R1[1] += b1*r1[9];  R1[2] += b2*r1[10]; R1[3] += b3*r1[11];
    R1[4] += b4*r1[12]; R1[5] += b5*r1[13]; R1[6] += b6*r1[14]; R1[7] += b7*r1[15];
  }
  #pragma unroll 4
  for (int i = Lc; i < L0; i++) {
    int j0 = s0 + i;
    const float* r0 = edata + (size_t)j0 * 48;
    int sd0 = esend[j0];
    float ch0 = chi[sd0*9 + cc];
    const uint4 q0 = Abf2[(size_t)sd0*180 + tt];
    float p0 = r0[16+ll] * r0[36+cc];
    float pc0 = p0 * ch0;
    #pragma unroll
    for (int r = 0; r < 8; r++) { A0[r] += r0[r] * p0; S0[r] += r0[r] * pc0; }
    float a0 = __uint_as_float(q0.x << 16), a1 = __uint_as_float(q0.x & 0xffff0000u);
    float a2 = __uint_as_float(q0.y << 16), a3 = __uint_as_float(q0.y & 0xffff0000u);
    float a4 = __uint_as_float(q0.z << 16), a5 = __uint_as_float(q0.z & 0xffff0000u);
    float a6 = __uint_as_float(q0.w << 16), a7 = __uint_as_float(q0.w & 0xffff0000u);
    R0[0] += a0*r0[8];  R0[1] += a1*r0[9];  R0[2] += a2*r0[10]; R0[3] += a3*r0[11];
    R0[4] += a4*r0[12]; R0[5] += a5*r0[13]; R0[6] += a6*r0[14]; R0[7] += a7*r0[15];
  }
  #pragma unroll 4
  for (int i = Lc; i < L1; i++) {
    int j1 = m0 + i;
    const float* r1 = edata + (size_t)j1 * 48;
    int sd1 = esend[j1];
    float ch1 = chi[sd1*9 + cc];
    const uint4 q1 = Abf2[(size_t)sd1*180 + tt];
    float p1 = r1[16+ll] * r1[36+cc];
    float pc1 = p1 * ch1;
    #pragma unroll
    for (int r = 0; r < 8; r++) { A1[r] += r1[r] * p1; S1[r] += r1[r] * pc1; }
    float b0 = __uint_as_float(q1.x << 16), b1 = __uint_as_float(q1.x & 0xffff0000u);
    float b2 = __uint_as_float(q1.y << 16), b3 = __uint_as_float(q1.y & 0xffff0000u);
    float b4 = __uint_as_float(q1.z << 16), b5 = __uint_as_float(q1.z & 0xffff0000u);
    float b6 = __uint_as_float(q1.w << 16), b7 = __uint_as_float(q1.w & 0xffff0000u);
    R1[0] += b0*r1[8];  R1[1] += b1*r1[9];  R1[2] += b2*r1[10]; R1[3] += b3*r1[11];
    R1[4] += b4*r1[12]; R1[5] += b5*r1[13]; R1[6] += b6*r1[14]; R1[7] += b7*r1[15];
  }
  __syncthreads();
  int deg = act ? d_DEGS[ll] : 0;
  float mlt = d_MULTI[ll]; int kk = 1 + deg;
  const float* wrp = &wr_s[deg*72];
  const float* wmp = &wm_s[deg*72];
  #pragma unroll
  for (int q = 0; q < 2; q++) {
    int n = n0 + q;
    if (n >= N) break;
    if (act) {
      const float* Aq = q ? A1 : A0;
      const float* Sq = q ? S1 : S0;
      const float* Rq = q ? R1 : R0;
      float Ab[8];                           // phase-1 A, rebuilt locally
      #pragma unroll
      for (int b = 0; b < 8; b++) {
        float a = 0.0f;
        #pragma unroll
        for (int r = 0; r < 8; r++) a += Aq[r] * wrp[r*8+b];
        Ab[b] = a;
      }
      float newA[8];
      #pragma unroll
      for (int b = 0; b < 8; b++) {
        float mem = 0.0f, ab = 0.0f;
        #pragma unroll
        for (int r = 0; r < 8; r++) { mem += Ab[r]*wmp[r*8+b]; ab += Sq[r]*wrp[r*8+b]; }
        newA[b] = (Rq[b] + ab)*MPNORM + mem;
      }
      if (l == 0) {
        #pragma unroll
        for (int b = 0; b < 8; b++) {
          Bsh[q][b*45 + c] = Ab[b];
          Bsh[2+q][b*45 + c] = newA[b];
        }
      }
      #pragma unroll
      for (int b = 0; b < 8; b++) {
        atomicAdd(&Bsh[q][b*45 + kk*9 + c], mlt*Ab[b]*Ab[b]);
        atomicAdd(&Bsh[2+q][b*45 + kk*9 + c], mlt*newA[b]*newA[b]);
      }
    }
  }
  __syncthreads();
  float2* out2 = reinterpret_cast<float2*>(out);
  int tot = (n1 < N) ? 720 : 360;
  for (int i = t; i < tot; i += 192) {
    float2 pk;
    pk.x = (&Bsh[0][0])[i];                  // phase-1 B (rebuilt)
    pk.y = (&Bsh[2][0])[i];                  // phase-2 B
    out2[(size_t)n0*360 + i] = pk;           // coalesced 8B stores
  }
}

extern "C" void kernel_launch(void* const* d_in, const int* in_sizes, int n_in,
                              void* d_out, int out_size, void* d_ws, size_t ws_size,
                              hipStream_t stream) {
  const float* pos    = (const float*)d_in[0];
  const float* shifts = (const float*)d_in[1];
  const float* Wemb   = (const float*)d_in[2];
  const float* Wrad   = (const float*)d_in[3];
  const float* Wmem   = (const float*)d_in[4];
  const float* War    = (const float*)d_in[5];
  const float* Wchi   = (const float*)d_in[6];
  const int* species = (const int*)d_in[7];
  const int* eidx    = (const int*)d_in[8];
  float* out = (float*)d_out;
  int N = in_sizes[7];
  int E = in_sizes[8] / 2;

  char* base = (char*)d_ws;
  size_t off = 0;
  float* edata = (float*)(base + off); off += (size_t)E*48*4;          // 9.6 MB (CSR-sorted)
  uint4* Abf2  = (uint4*)(base + off); off += (size_t)N*180*16;        // 5.76 MB packed
  float* chi   = (float*)(base + off); off += (size_t)N*9*4;
  int* offs    = (int*)(base + off);   off += (((size_t)(N+1)*4) + 15) & ~(size_t)15;
  int* esend   = (int*)(base + off);   off += (size_t)E*4;
  int* erank   = (int*)(base + off);   off += (((size_t)E*4) + 15) & ~(size_t)15;

  int G = (N + 1) / 2;
  k_prep<<<1, 1024, 0, stream>>>(eidx, offs, erank, N, E);
  k_edge<<<(E + 63) / 64, 64, 0, stream>>>(pos, shifts, Wemb, War, species, eidx,
                                           offs, erank, edata, esend, E);
  k_nodeA<<<G, 192, 0, stream>>>(edata, offs, Wrad, Wchi, Abf2, chi, N);
  k_node2<<<G, 192, 0, stream>>>(edata, esend, offs, Wrad, Wmem, Abf2, chi, out, N);
}